// Round 3
// baseline (134.273 us; speedup 1.0000x reference)
//
#include <hip/hip_runtime.h>
#include <hip/hip_bf16.h>
#include <cstdint>

#define HEADS 12

typedef __attribute__((ext_vector_type(8))) __bf16 bf16x8;
typedef __attribute__((ext_vector_type(4))) __bf16 bf16x4;
typedef __attribute__((ext_vector_type(4))) float f32x4;

#define AS1 __attribute__((address_space(1)))
#define AS3 __attribute__((address_space(3)))

__device__ __forceinline__ void gload16(const void* src, void* lds) {
  __builtin_amdgcn_global_load_lds((AS1 void*)src, (AS3 void*)lds, 16, 0, 0);
}

__device__ __forceinline__ uint32_t cvtpk(float lo, float hi) {
  uint32_t r;
  asm("v_cvt_pk_bf16_f32 %0, %1, %2" : "=v"(r) : "v"(lo), "v"(hi));
  return r;
}

__device__ __forceinline__ float exp2_fast(float x) {
  float r;
  asm("v_exp_f32 %0, %1" : "=v"(r) : "v"(x));
  return r;
}

// ---------------- cast fp32 -> bf16 (flat, vectorized) ----------------
__global__ void k_cast(const float* __restrict__ in, __bf16* __restrict__ out, int n) {
  int i = (blockIdx.x * 256 + threadIdx.x) * 4;
  if (i + 3 < n) {
    float4 v = *(const float4*)(in + i);
    bf16x4 o;
    o[0] = (__bf16)v.x; o[1] = (__bf16)v.y; o[2] = (__bf16)v.z; o[3] = (__bf16)v.w;
    *(bf16x4*)(out + i) = o;
  }
}

// ------------- transpose+cast weight: W[K][N] f32 -> Wt[N][K] bf16 (×scale) -------------
__global__ void k_twc(const float* __restrict__ W, __bf16* __restrict__ Wt, int K, int N, float scale) {
  __shared__ float tile[32][33];
  int nt = blockIdx.x, kt = blockIdx.y;
  int c = threadIdx.x & 31, r0 = threadIdx.x >> 5;
#pragma unroll
  for (int i = 0; i < 4; ++i) {
    int r = r0 + i * 8;
    tile[r][c] = W[(size_t)(kt * 32 + r) * N + nt * 32 + c];
  }
  __syncthreads();
#pragma unroll
  for (int i = 0; i < 4; ++i) {
    int r = r0 + i * 8;
    Wt[(size_t)(nt * 32 + r) * K + kt * 32 + c] = (__bf16)(tile[c][r] * scale);
  }
}

// ------------- transpose V slice of kv into vT[b][h*64+d][m] (bf16) -------------
__global__ void k_tv(const __bf16* __restrict__ kv, __bf16* __restrict__ vT) {
  __shared__ __bf16 tile[32][33];
  int mt = blockIdx.x, ct = blockIdx.y, b = blockIdx.z;
  int c = threadIdx.x & 31, r0 = threadIdx.x >> 5;
#pragma unroll
  for (int i = 0; i < 4; ++i) {
    int r = r0 + i * 8;  // m-local
    tile[r][c] = kv[((size_t)(b * 1024 + mt * 32 + r)) * 1536 + 768 + ct * 32 + c];
  }
  __syncthreads();
#pragma unroll
  for (int i = 0; i < 4; ++i) {
    int r = r0 + i * 8;  // c-local
    vT[((size_t)(b * 768 + ct * 32 + r)) * 1024 + mt * 32 + c] = tile[c][r];
  }
}

// ---------------- bf16 GEMM: C[M][N] = A[M][K] * Bt[N][K]^T ----------------
// 128x128 tile, BK=64, 4 waves. XCD-aware block swizzle (grid % 8 == 0 required).
template<bool BF16OUT>
__global__ __launch_bounds__(256, 2) void k_gemm(
    const __bf16* __restrict__ A, const __bf16* __restrict__ Bt,
    void* __restrict__ C, const float* __restrict__ bias, int M, int N, int K) {
  __shared__ __align__(16) char ldsA[2][16384];
  __shared__ __align__(16) char ldsB[2][16384];
  const int tid = threadIdx.x;
  const int ln = tid & 63;
  const int w = tid >> 6;
  // XCD swizzle: contiguous work chunk per XCD (nwg % 8 == 0 for all our grids)
  const int nwx = gridDim.x;
  int bid = blockIdx.y * nwx + blockIdx.x;
  const int cpx = (nwx * gridDim.y) >> 3;
  bid = (bid & 7) * cpx + (bid >> 3);
  const int bm0 = (bid / nwx) * 128, bn0 = (bid % nwx) * 128;
  const int wm0 = (w >> 1) * 64, wn0 = (w & 1) * 64;

  auto stage = [&](char* lds, const __bf16* G, int row0, int k0) {
    const char* gb = (const char*)(G + (size_t)row0 * K + k0);
#pragma unroll
    for (int c = 0; c < 4; ++c) {
      int off = c * 4096 + tid * 16;
      int row = off >> 7;
      int s = ((off >> 4) & 7) ^ (row & 7);
      gload16(gb + (size_t)row * (K * 2) + (s << 4), lds + c * 4096 + (w << 10));
    }
  };

  f32x4 acc[4][4] = {};
  const int NK = K >> 6;
  stage(ldsA[0], A, bm0, 0);
  stage(ldsB[0], Bt, bn0, 0);
  __syncthreads();
  for (int kt = 0; kt < NK; ++kt) {
    const char* bufA = ldsA[kt & 1];
    const char* bufB = ldsB[kt & 1];
    if (kt + 1 < NK) {
      stage(ldsA[(kt + 1) & 1], A, bm0, (kt + 1) << 6);
      stage(ldsB[(kt + 1) & 1], Bt, bn0, (kt + 1) << 6);
    }
    bf16x8 af[2][4], bf[2][4];
#pragma unroll
    for (int kk = 0; kk < 2; ++kk)
#pragma unroll
      for (int mt = 0; mt < 4; ++mt) {
        int row = wm0 + mt * 16 + (ln & 15);
        af[kk][mt] = *(const bf16x8*)(bufA + row * 128 + (((kk * 4 + (ln >> 4)) ^ (row & 7)) << 4));
      }
#pragma unroll
    for (int kk = 0; kk < 2; ++kk)
#pragma unroll
      for (int nt = 0; nt < 4; ++nt) {
        int row = wn0 + nt * 16 + (ln & 15);
        bf[kk][nt] = *(const bf16x8*)(bufB + row * 128 + (((kk * 4 + (ln >> 4)) ^ (row & 7)) << 4));
      }
#pragma unroll
    for (int kk = 0; kk < 2; ++kk)
#pragma unroll
      for (int mt = 0; mt < 4; ++mt)
#pragma unroll
        for (int nt = 0; nt < 4; ++nt)
          acc[mt][nt] = __builtin_amdgcn_mfma_f32_16x16x32_bf16(af[kk][mt], bf[kk][nt], acc[mt][nt], 0, 0, 0);
    __syncthreads();
  }
#pragma unroll
  for (int mt = 0; mt < 4; ++mt) {
    int row = bm0 + wm0 + mt * 16 + ((ln >> 4) << 2);
#pragma unroll
    for (int nt = 0; nt < 4; ++nt) {
      int col = bn0 + wn0 + nt * 16 + (ln & 15);
      if (BF16OUT) {
        __bf16* Cb = (__bf16*)C;
#pragma unroll
        for (int jj = 0; jj < 4; ++jj)
          Cb[(size_t)(row + jj) * N + col] = (__bf16)acc[mt][nt][jj];
      } else {
        float* Cf = (float*)C;
        float bv = bias[col];
#pragma unroll
        for (int jj = 0; jj < 4; ++jj)
          Cf[(size_t)(row + jj) * N + col] = acc[mt][nt][jj] + bv;
      }
    }
  }
}

// ---------------- flash attention, swapped-operand, 3-deep pipeline ----------------
// block = 128 q rows x (b,h), 4 waves x 32 q rows. Q pre-scaled by SCALE*log2(e).
// S^T = mfma(K,Q); softmax in exp2 domain, defer-max (THR=8 log2), lane-partial lrow
// (sum-reduce deferred to epilogue). O^T = mfma(V^T, P^T). K/V triple-buffered,
// counted vmcnt(4) before each barrier (T4).
__global__ __launch_bounds__(256, 4) void k_attn(
    const __bf16* __restrict__ q, const __bf16* __restrict__ kv,
    const __bf16* __restrict__ vT, __bf16* __restrict__ ao) {
  __shared__ __align__(16) char ldsK[3][8192];
  __shared__ __align__(16) char ldsV[3][8192];
  const int tid = threadIdx.x, ln = tid & 63, w = tid >> 6, g = ln >> 4;
  const int qt = blockIdx.x, bh = blockIdx.y;
  const int b = bh / HEADS, h = bh % HEADS;
  const int qbase = b * 2048 + qt * 128 + w * 32;

  const char* kgb = (const char*)(kv + ((size_t)b * 1024) * 1536 + h * 64);
  const char* vgb = (const char*)(vT + ((size_t)(b * 768 + h * 64)) * 1024);

  auto stageKV = [&](int t, int buf) {
#pragma unroll
    for (int c = 0; c < 2; ++c) {
      int off = c * 4096 + tid * 16;
      int row = off >> 7;
      int s = ((off >> 4) & 7) ^ (row & 7);
      gload16(kgb + (size_t)(t * 64 + row) * 3072 + (s << 4), ldsK[buf] + c * 4096 + w * 1024);
      gload16(vgb + (size_t)row * 2048 + (size_t)t * 128 + (s << 4), ldsV[buf] + c * 4096 + w * 1024);
    }
  };

  stageKV(0, 0);
  stageKV(1, 1);

  // Q fragments direct to registers (pre-scaled by SCALE*log2e in k_twc)
  bf16x8 qf[2][2];
#pragma unroll
  for (int m = 0; m < 2; ++m)
#pragma unroll
    for (int kk = 0; kk < 2; ++kk)
      qf[m][kk] = *(const bf16x8*)(q + (size_t)(qbase + m * 16 + (ln & 15)) * 768 + h * 64 + (kk * 4 + g) * 8);

  f32x4 acc[2][4] = {};
  float mrow[2] = {-1e30f, -1e30f};
  float lrow[2] = {0.f, 0.f};  // lane-partial (this lane's kv slice); reduced in epilogue

  asm volatile("s_waitcnt vmcnt(8)" ::: "memory");  // stage(0) landed (own 4 loads)
  __builtin_amdgcn_s_barrier();

  for (int t = 0; t < 16; ++t) {
    if (t < 14) stageKV(t + 2, (t + 2) % 3);
    const char* bufK = ldsK[t % 3];
    const char* bufV = ldsV[t % 3];

    // S^T = K . Q^T
    f32x4 sf[2][4] = {};
    __builtin_amdgcn_s_setprio(1);
#pragma unroll
    for (int kk = 0; kk < 2; ++kk)
#pragma unroll
      for (int nt = 0; nt < 4; ++nt) {
        int row = nt * 16 + (ln & 15);
        bf16x8 kf = *(const bf16x8*)(bufK + row * 128 + (((kk * 4 + g) ^ (row & 7)) << 4));
        sf[0][nt] = __builtin_amdgcn_mfma_f32_16x16x32_bf16(kf, qf[0][kk], sf[0][nt], 0, 0, 0);
        sf[1][nt] = __builtin_amdgcn_mfma_f32_16x16x32_bf16(kf, qf[1][kk], sf[1][nt], 0, 0, 0);
      }
    __builtin_amdgcn_s_setprio(0);

    // online softmax (exp2 domain). lane owns q=(ln&15), kv slice {16nt+4g+jj}
    bf16x8 pb[2][2];
#pragma unroll
    for (int m = 0; m < 2; ++m) {
      float lm = sf[m][0][0];
#pragma unroll
      for (int nt = 0; nt < 4; ++nt)
#pragma unroll
        for (int jj = 0; jj < 4; ++jj) lm = fmaxf(lm, sf[m][nt][jj]);
      // defer-max: skip reduce+rescale when local growth is small (wave-uniform)
      if (!__all(lm <= mrow[m] + 8.0f)) {
        float mx = lm;
        mx = fmaxf(mx, __shfl_xor(mx, 16, 64));
        mx = fmaxf(mx, __shfl_xor(mx, 32, 64));
        float mn = fmaxf(mrow[m], mx);
        float corr = exp2_fast(mrow[m] - mn);
        mrow[m] = mn;
        lrow[m] *= corr;
#pragma unroll
        for (int dt = 0; dt < 4; ++dt) acc[m][dt] *= corr;
      }
      float p[4][4];
      f32x4 ps = {0.f, 0.f, 0.f, 0.f};
#pragma unroll
      for (int nt = 0; nt < 4; ++nt)
#pragma unroll
        for (int jj = 0; jj < 4; ++jj) {
          float e = exp2_fast(sf[m][nt][jj] - mrow[m]);
          p[nt][jj] = e;
          ps[jj] += e;
        }
      lrow[m] += (ps[0] + ps[1]) + (ps[2] + ps[3]);

      // pack P^T fragments: cvt_pk + permlane32/16 swap cascade
      uint32_t c0[4], c1[4];
#pragma unroll
      for (int nt = 0; nt < 4; ++nt) {
        c0[nt] = cvtpk(p[nt][0], p[nt][1]);
        c1[nt] = cvtpk(p[nt][2], p[nt][3]);
      }
#pragma unroll
      for (int kk = 0; kk < 2; ++kk) {
        uint32_t x0 = c0[2 * kk], y0 = c0[2 * kk + 1];
        asm("v_permlane32_swap_b32 %0, %1" : "+v"(x0), "+v"(y0));
        asm("v_permlane16_swap_b32 %0, %1" : "+v"(x0), "+v"(y0));
        uint32_t x1 = c1[2 * kk], y1 = c1[2 * kk + 1];
        asm("v_permlane32_swap_b32 %0, %1" : "+v"(x1), "+v"(y1));
        asm("v_permlane16_swap_b32 %0, %1" : "+v"(x1), "+v"(y1));
        union { uint32_t u[4]; bf16x8 v; } pk;
        pk.u[0] = x0; pk.u[1] = x1; pk.u[2] = y0; pk.u[3] = y1;
        pb[m][kk] = pk.v;
      }
    }

    // O^T += V^T . P^T
    __builtin_amdgcn_s_setprio(1);
#pragma unroll
    for (int kk = 0; kk < 2; ++kk)
#pragma unroll
      for (int dt = 0; dt < 4; ++dt) {
        int row = dt * 16 + (ln & 15);
        bf16x8 vf = *(const bf16x8*)(bufV + row * 128 + (((kk * 4 + g) ^ (row & 7)) << 4));
        acc[0][dt] = __builtin_amdgcn_mfma_f32_16x16x32_bf16(vf, pb[0][kk], acc[0][dt], 0, 0, 0);
        acc[1][dt] = __builtin_amdgcn_mfma_f32_16x16x32_bf16(vf, pb[1][kk], acc[1][dt], 0, 0, 0);
      }
    __builtin_amdgcn_s_setprio(0);

    if (t < 14) {
      asm volatile("s_waitcnt vmcnt(4)" ::: "memory");  // t+1's loads landed; t+2 in flight
      __builtin_amdgcn_s_barrier();
    } else if (t == 14) {
      asm volatile("s_waitcnt vmcnt(0)" ::: "memory");
      __builtin_amdgcn_s_barrier();
    }
  }

  // epilogue: reduce lane-partial lrow across the 4 kv groups, then write O
#pragma unroll
  for (int m = 0; m < 2; ++m) {
    float l = lrow[m];
    l += __shfl_xor(l, 16, 64);
    l += __shfl_xor(l, 32, 64);
    float inv = 1.0f / l;
    size_t rowb = (size_t)(qbase + m * 16 + (ln & 15)) * 768 + h * 64;
#pragma unroll
    for (int dt = 0; dt < 4; ++dt) {
      bf16x4 o;
#pragma unroll
      for (int jj = 0; jj < 4; ++jj) o[jj] = (__bf16)(acc[m][dt][jj] * inv);
      *(bf16x4*)(ao + rowb + 16 * dt + 4 * g) = o;
    }
  }
}

extern "C" void kernel_launch(void* const* d_in, const int* in_sizes, int n_in,
                              void* d_out, int out_size, void* d_ws, size_t ws_size,
                              hipStream_t stream) {
  const float* x = (const float*)d_in[0];
  const float* r = (const float*)d_in[1];
  const float* Wq = (const float*)d_in[2];
  const float* Wkv = (const float*)d_in[3];
  const float* Wp = (const float*)d_in[4];
  const float* bp = (const float*)d_in[5];

  char* ws = (char*)d_ws;
  __bf16* xb  = (__bf16*)ws; ws += (size_t)6291456 * 2;  // x bf16 (8192x768)
  __bf16* rb  = (__bf16*)ws; ws += (size_t)3145728 * 2;  // r bf16 (4096x768)
  __bf16* wqt = (__bf16*)ws; ws += (size_t)589824 * 2;   // W_q^T * SCALE*log2e
  __bf16* wkvt= (__bf16*)ws; ws += (size_t)1179648 * 2;  // W_kv^T (1536x768)
  __bf16* wpt = (__bf16*)ws; ws += (size_t)589824 * 2;   // W_proj^T (768x768)
  __bf16* qb  = (__bf16*)ws; ws += (size_t)6291456 * 2;  // q (8192x768), pre-scaled
  __bf16* kvb = (__bf16*)ws; ws += (size_t)6291456 * 2;  // kv (4096x1536)
  __bf16* vT  = (__bf16*)ws; ws += (size_t)3145728 * 2;  // v^T (4 x 768 x 1024)
  __bf16* ao  = (__bf16*)ws;                              // attn out (8192x768)

  k_cast<<<6144, 256, 0, stream>>>(x, xb, 6291456);
  k_cast<<<3072, 256, 0, stream>>>(r, rb, 3145728);
  // 0.125 * log2(e) = 0.1803368801 : QK^T lands directly in exp2 domain
  k_twc<<<dim3(24, 24), 256, 0, stream>>>(Wq, wqt, 768, 768, 0.18033688011112042f);
  k_twc<<<dim3(48, 24), 256, 0, stream>>>(Wkv, wkvt, 768, 1536, 1.0f);
  k_twc<<<dim3(24, 24), 256, 0, stream>>>(Wp, wpt, 768, 768, 1.0f);
  k_gemm<true><<<dim3(6, 64), 256, 0, stream>>>(xb, wqt, qb, nullptr, 8192, 768, 768);
  k_gemm<true><<<dim3(12, 32), 256, 0, stream>>>(rb, wkvt, kvb, nullptr, 4096, 1536, 768);
  k_tv<<<dim3(32, 24, 4), 256, 0, stream>>>(kvb, vT);
  k_attn<<<dim3(16, 48), 256, 0, stream>>>(qb, kvb, vT, ao);
  k_gemm<false><<<dim3(6, 64), 256, 0, stream>>>(ao, wpt, d_out, bp, 8192, 768, 768);
}

// Round 4
// 112.206 us; speedup vs baseline: 1.1967x; 1.1967x over previous
//
#include <hip/hip_runtime.h>
#include <hip/hip_bf16.h>
#include <cstdint>

#define HEADS 12

typedef __attribute__((ext_vector_type(8))) __bf16 bf16x8;
typedef __attribute__((ext_vector_type(4))) __bf16 bf16x4;
typedef __attribute__((ext_vector_type(4))) float f32x4;

#define AS1 __attribute__((address_space(1)))
#define AS3 __attribute__((address_space(3)))

__device__ __forceinline__ void gload16(const void* src, void* lds) {
  __builtin_amdgcn_global_load_lds((AS1 void*)src, (AS3 void*)lds, 16, 0, 0);
}

__device__ __forceinline__ uint32_t cvtpk(float lo, float hi) {
  uint32_t r;
  asm("v_cvt_pk_bf16_f32 %0, %1, %2" : "=v"(r) : "v"(lo), "v"(hi));
  return r;
}

__device__ __forceinline__ float exp2_fast(float x) {
  float r;
  asm("v_exp_f32 %0, %1" : "=v"(r) : "v"(x));
  return r;
}

// ---------------- cast fp32 -> bf16: x (6291456) then r (3145728) ----------------
__global__ void k_cast2(const float* __restrict__ x, const float* __restrict__ r,
                        __bf16* __restrict__ xb, __bf16* __restrict__ rb) {
  int i = (blockIdx.x * 256 + threadIdx.x) * 4;
  const float* src;
  __bf16* dst;
  int off;
  if (i < 6291456) { src = x; dst = xb; off = i; }
  else             { src = r; dst = rb; off = i - 6291456; }
  float4 v = *(const float4*)(src + off);
  bf16x4 o;
  o[0] = (__bf16)v.x; o[1] = (__bf16)v.y; o[2] = (__bf16)v.z; o[3] = (__bf16)v.w;
  *(bf16x4*)(dst + off) = o;
}

// ------------- transpose+cast all 3 weights: W[K][N] f32 -> Wt[N][K] bf16 (×scale) -------------
__global__ void k_twc3(const float* __restrict__ Wq, const float* __restrict__ Wkv,
                       const float* __restrict__ Wp, __bf16* __restrict__ wqt,
                       __bf16* __restrict__ wkvt, __bf16* __restrict__ wpt) {
  __shared__ float tile[32][33];
  const float* W; __bf16* Wt; int N; float scale;
  if (blockIdx.z == 0)      { W = Wq;  Wt = wqt;  N = 768;  scale = 0.18033688011112042f; }
  else if (blockIdx.z == 1) { W = Wkv; Wt = wkvt; N = 1536; scale = 1.0f; }
  else                      { W = Wp;  Wt = wpt;  N = 768;  scale = 1.0f; }
  int nt = blockIdx.x, kt = blockIdx.y;
  if (nt * 32 >= N) return;
  int c = threadIdx.x & 31, r0 = threadIdx.x >> 5;
#pragma unroll
  for (int i = 0; i < 4; ++i) {
    int r = r0 + i * 8;
    tile[r][c] = W[(size_t)(kt * 32 + r) * N + nt * 32 + c];
  }
  __syncthreads();
#pragma unroll
  for (int i = 0; i < 4; ++i) {
    int r = r0 + i * 8;
    Wt[(size_t)(nt * 32 + r) * 768 + kt * 32 + c] = (__bf16)(tile[c][r] * scale);
  }
}

// ---------------- bf16 GEMM: C[M][N] = A[M][K] * Bt[N][K]^T ----------------
// 128x128 tile, BK=64, 4 waves. XCD-aware swizzle. Optional transposed-V side-write:
// if vTp != null, columns >= 768 are written ONLY to vTp[b*768 + (col-768)][row%1024].
template<bool BF16OUT>
__global__ __launch_bounds__(256, 2) void k_gemm(
    const __bf16* __restrict__ A, const __bf16* __restrict__ Bt,
    void* __restrict__ C, const float* __restrict__ bias, __bf16* __restrict__ vTp,
    int M, int N, int K) {
  __shared__ __align__(16) char ldsA[2][16384];
  __shared__ __align__(16) char ldsB[2][16384];
  const int tid = threadIdx.x;
  const int ln = tid & 63;
  const int w = tid >> 6;
  const int nwx = gridDim.x;
  int bid = blockIdx.y * nwx + blockIdx.x;
  const int cpx = (nwx * gridDim.y) >> 3;
  bid = (bid & 7) * cpx + (bid >> 3);
  const int bm0 = (bid / nwx) * 128, bn0 = (bid % nwx) * 128;
  const int wm0 = (w >> 1) * 64, wn0 = (w & 1) * 64;

  auto stage = [&](char* lds, const __bf16* G, int row0, int k0) {
    const char* gb = (const char*)(G + (size_t)row0 * K + k0);
#pragma unroll
    for (int c = 0; c < 4; ++c) {
      int off = c * 4096 + tid * 16;
      int row = off >> 7;
      int s = ((off >> 4) & 7) ^ (row & 7);
      gload16(gb + (size_t)row * (K * 2) + (s << 4), lds + c * 4096 + (w << 10));
    }
  };

  f32x4 acc[4][4] = {};
  const int NK = K >> 6;
  stage(ldsA[0], A, bm0, 0);
  stage(ldsB[0], Bt, bn0, 0);
  __syncthreads();
  for (int kt = 0; kt < NK; ++kt) {
    const char* bufA = ldsA[kt & 1];
    const char* bufB = ldsB[kt & 1];
    if (kt + 1 < NK) {
      stage(ldsA[(kt + 1) & 1], A, bm0, (kt + 1) << 6);
      stage(ldsB[(kt + 1) & 1], Bt, bn0, (kt + 1) << 6);
    }
    bf16x8 af[2][4], bf[2][4];
#pragma unroll
    for (int kk = 0; kk < 2; ++kk)
#pragma unroll
      for (int mt = 0; mt < 4; ++mt) {
        int row = wm0 + mt * 16 + (ln & 15);
        af[kk][mt] = *(const bf16x8*)(bufA + row * 128 + (((kk * 4 + (ln >> 4)) ^ (row & 7)) << 4));
      }
#pragma unroll
    for (int kk = 0; kk < 2; ++kk)
#pragma unroll
      for (int nt = 0; nt < 4; ++nt) {
        int row = wn0 + nt * 16 + (ln & 15);
        bf[kk][nt] = *(const bf16x8*)(bufB + row * 128 + (((kk * 4 + (ln >> 4)) ^ (row & 7)) << 4));
      }
    __builtin_amdgcn_s_setprio(1);
#pragma unroll
    for (int kk = 0; kk < 2; ++kk)
#pragma unroll
      for (int mt = 0; mt < 4; ++mt)
#pragma unroll
        for (int nt = 0; nt < 4; ++nt)
          acc[mt][nt] = __builtin_amdgcn_mfma_f32_16x16x32_bf16(af[kk][mt], bf[kk][nt], acc[mt][nt], 0, 0, 0);
    __builtin_amdgcn_s_setprio(0);
    __syncthreads();
  }
#pragma unroll
  for (int mt = 0; mt < 4; ++mt) {
    int row = bm0 + wm0 + mt * 16 + ((ln >> 4) << 2);
#pragma unroll
    for (int nt = 0; nt < 4; ++nt) {
      int col = bn0 + wn0 + nt * 16 + (ln & 15);
      if (BF16OUT) {
        if (vTp != nullptr && bn0 >= 768) {
          // V part: write transposed into vT[b*768 + (col-768)][row & 1023]
          bf16x4 o;
#pragma unroll
          for (int jj = 0; jj < 4; ++jj) o[jj] = (__bf16)acc[mt][nt][jj];
          *(bf16x4*)(vTp + ((size_t)((row >> 10) * 768 + col - 768)) * 1024 + (row & 1023)) = o;
        } else {
          __bf16* Cb = (__bf16*)C;
#pragma unroll
          for (int jj = 0; jj < 4; ++jj)
            Cb[(size_t)(row + jj) * N + col] = (__bf16)acc[mt][nt][jj];
        }
      } else {
        float* Cf = (float*)C;
        float bv = bias[col];
#pragma unroll
        for (int jj = 0; jj < 4; ++jj)
          Cf[(size_t)(row + jj) * N + col] = acc[mt][nt][jj] + bv;
      }
    }
  }
}

// ---------------- flash attention, 8-wave, swapped-operand, 3-deep pipeline ----------------
// block = 512 thr = 8 waves, each wave 16 q rows. KVBLK=64, 16 tiles.
// Q pre-scaled by SCALE*log2e. S^T = mfma(K,Q); exp2-domain online softmax with
// defer-max; lane-partial lrow (reduced in epilogue); P^T via cvt_pk+permlane;
// O^T = mfma(V^T,P^T). K/V triple-buffered (48KB), counted vmcnt(2) per tile.
__global__ __launch_bounds__(512, 6) void k_attn(
    const __bf16* __restrict__ q, const __bf16* __restrict__ kv,
    const __bf16* __restrict__ vT, __bf16* __restrict__ ao) {
  __shared__ __align__(16) char ldsK[3][8192];
  __shared__ __align__(16) char ldsV[3][8192];
  const int tid = threadIdx.x, ln = tid & 63, w = tid >> 6, g = ln >> 4;
  const int qt = blockIdx.x, bh = blockIdx.y;
  const int b = bh / HEADS, h = bh % HEADS;
  const int qrow = b * 2048 + qt * 128 + w * 16 + (ln & 15);

  const char* kgb = (const char*)(kv + ((size_t)b * 1024) * 1536 + h * 64);
  const char* vgb = (const char*)(vT + ((size_t)(b * 768 + h * 64)) * 1024);

  const int srow = tid >> 3;                        // 0..63
  const int scol = (((tid & 7) ^ (srow & 7)) << 4); // swizzled byte col
  const int ldst = w * 1024;                        // wave-uniform LDS base

  auto stageKV = [&](int t, int buf) {
    gload16(kgb + (size_t)(t * 64 + srow) * 3072 + scol, ldsK[buf] + ldst);
    gload16(vgb + (size_t)srow * 2048 + (size_t)t * 128 + scol, ldsV[buf] + ldst);
  };

  // Q fragments direct to registers (pre-scaled by SCALE*log2e)
  bf16x8 qf[2];
#pragma unroll
  for (int kk = 0; kk < 2; ++kk)
    qf[kk] = *(const bf16x8*)(q + (size_t)qrow * 768 + h * 64 + (kk * 4 + g) * 8);

  stageKV(0, 0);
  stageKV(1, 1);

  f32x4 acc[4] = {};
  float mrow = -1e30f, lrow = 0.f;

  asm volatile("s_waitcnt vmcnt(2)" ::: "memory");  // stage(0) landed
  __builtin_amdgcn_s_barrier();

  for (int t = 0; t < 16; ++t) {
    if (t < 14) stageKV(t + 2, (t + 2) % 3);
    const char* bufK = ldsK[t % 3];
    const char* bufV = ldsV[t % 3];

    // S^T = K . Q^T
    f32x4 sf[4] = {};
    __builtin_amdgcn_s_setprio(1);
#pragma unroll
    for (int kk = 0; kk < 2; ++kk)
#pragma unroll
      for (int nt = 0; nt < 4; ++nt) {
        int row = nt * 16 + (ln & 15);
        bf16x8 kf = *(const bf16x8*)(bufK + row * 128 + (((kk * 4 + g) ^ (row & 7)) << 4));
        sf[nt] = __builtin_amdgcn_mfma_f32_16x16x32_bf16(kf, qf[kk], sf[nt], 0, 0, 0);
      }
    __builtin_amdgcn_s_setprio(0);

    // online softmax (exp2 domain); lane owns q=(ln&15), kv slice {16nt+4g+jj}
    float lm = sf[0][0];
#pragma unroll
    for (int nt = 0; nt < 4; ++nt)
#pragma unroll
      for (int jj = 0; jj < 4; ++jj) lm = fmaxf(lm, sf[nt][jj]);
    if (!__all(lm <= mrow + 8.0f)) {
      float mx = lm;
      mx = fmaxf(mx, __shfl_xor(mx, 16, 64));
      mx = fmaxf(mx, __shfl_xor(mx, 32, 64));
      float mn = fmaxf(mrow, mx);
      float corr = exp2_fast(mrow - mn);
      mrow = mn;
      lrow *= corr;
#pragma unroll
      for (int dt = 0; dt < 4; ++dt) acc[dt] *= corr;
    }
    float p[4][4];
    f32x4 ps = {0.f, 0.f, 0.f, 0.f};
#pragma unroll
    for (int nt = 0; nt < 4; ++nt)
#pragma unroll
      for (int jj = 0; jj < 4; ++jj) {
        float e = exp2_fast(sf[nt][jj] - mrow);
        p[nt][jj] = e;
        ps[jj] += e;
      }
    lrow += (ps[0] + ps[1]) + (ps[2] + ps[3]);

    // P^T fragments: cvt_pk + permlane32/16 swap cascade
    bf16x8 pb[2];
    uint32_t c0[4], c1[4];
#pragma unroll
    for (int nt = 0; nt < 4; ++nt) {
      c0[nt] = cvtpk(p[nt][0], p[nt][1]);
      c1[nt] = cvtpk(p[nt][2], p[nt][3]);
    }
#pragma unroll
    for (int kk = 0; kk < 2; ++kk) {
      uint32_t x0 = c0[2 * kk], y0 = c0[2 * kk + 1];
      asm("v_permlane32_swap_b32 %0, %1" : "+v"(x0), "+v"(y0));
      asm("v_permlane16_swap_b32 %0, %1" : "+v"(x0), "+v"(y0));
      uint32_t x1 = c1[2 * kk], y1 = c1[2 * kk + 1];
      asm("v_permlane32_swap_b32 %0, %1" : "+v"(x1), "+v"(y1));
      asm("v_permlane16_swap_b32 %0, %1" : "+v"(x1), "+v"(y1));
      union { uint32_t u[4]; bf16x8 v; } pk;
      pk.u[0] = x0; pk.u[1] = x1; pk.u[2] = y0; pk.u[3] = y1;
      pb[kk] = pk.v;
    }

    // O^T += V^T . P^T
    __builtin_amdgcn_s_setprio(1);
#pragma unroll
    for (int kk = 0; kk < 2; ++kk)
#pragma unroll
      for (int dt = 0; dt < 4; ++dt) {
        int row = dt * 16 + (ln & 15);
        bf16x8 vf = *(const bf16x8*)(bufV + row * 128 + (((kk * 4 + g) ^ (row & 7)) << 4));
        acc[dt] = __builtin_amdgcn_mfma_f32_16x16x32_bf16(vf, pb[kk], acc[dt], 0, 0, 0);
      }
    __builtin_amdgcn_s_setprio(0);

    if (t < 14) {
      asm volatile("s_waitcnt vmcnt(2)" ::: "memory");  // t+1 landed, t+2 in flight
      __builtin_amdgcn_s_barrier();
    } else if (t == 14) {
      asm volatile("s_waitcnt vmcnt(0)" ::: "memory");
      __builtin_amdgcn_s_barrier();
    }
  }

  // epilogue: reduce lane-partial lrow across the 4 kv groups, write O
  float l = lrow;
  l += __shfl_xor(l, 16, 64);
  l += __shfl_xor(l, 32, 64);
  float inv = 1.0f / l;
  size_t rowb = (size_t)qrow * 768 + h * 64;
#pragma unroll
  for (int dt = 0; dt < 4; ++dt) {
    bf16x4 o;
#pragma unroll
    for (int jj = 0; jj < 4; ++jj) o[jj] = (__bf16)(acc[dt][jj] * inv);
    *(bf16x4*)(ao + rowb + 16 * dt + 4 * g) = o;
  }
}

extern "C" void kernel_launch(void* const* d_in, const int* in_sizes, int n_in,
                              void* d_out, int out_size, void* d_ws, size_t ws_size,
                              hipStream_t stream) {
  const float* x = (const float*)d_in[0];
  const float* r = (const float*)d_in[1];
  const float* Wq = (const float*)d_in[2];
  const float* Wkv = (const float*)d_in[3];
  const float* Wp = (const float*)d_in[4];
  const float* bp = (const float*)d_in[5];

  char* ws = (char*)d_ws;
  __bf16* xb  = (__bf16*)ws; ws += (size_t)6291456 * 2;  // x bf16 (8192x768)
  __bf16* rb  = (__bf16*)ws; ws += (size_t)3145728 * 2;  // r bf16 (4096x768)
  __bf16* wqt = (__bf16*)ws; ws += (size_t)589824 * 2;   // W_q^T * SCALE*log2e
  __bf16* wkvt= (__bf16*)ws; ws += (size_t)1179648 * 2;  // W_kv^T (1536x768)
  __bf16* wpt = (__bf16*)ws; ws += (size_t)589824 * 2;   // W_proj^T (768x768)
  __bf16* qb  = (__bf16*)ws; ws += (size_t)6291456 * 2;  // q (8192x768), pre-scaled
  __bf16* kvb = (__bf16*)ws; ws += (size_t)6291456 * 2;  // kv (K half valid)
  __bf16* vT  = (__bf16*)ws; ws += (size_t)3145728 * 2;  // v^T (4 x 768 x 1024)
  __bf16* ao  = (__bf16*)ws;                              // attn out (8192x768)

  k_cast2<<<9216, 256, 0, stream>>>(x, r, xb, rb);
  k_twc3<<<dim3(48, 24, 3), 256, 0, stream>>>(Wq, Wkv, Wp, wqt, wkvt, wpt);
  k_gemm<true><<<dim3(6, 64), 256, 0, stream>>>(xb, wqt, qb, nullptr, nullptr, 8192, 768, 768);
  k_gemm<true><<<dim3(12, 32), 256, 0, stream>>>(rb, wkvt, kvb, nullptr, vT, 4096, 1536, 768);
  k_attn<<<dim3(16, 48), 512, 0, stream>>>(qb, kvb, vT, ao);
  k_gemm<false><<<dim3(6, 64), 256, 0, stream>>>(ao, wpt, d_out, bp, nullptr, 8192, 768, 768);
}